// Round 10
// baseline (257.968 us; speedup 1.0000x reference)
//
#include <hip/hip_runtime.h>

typedef __bf16 bf16;
typedef __attribute__((ext_vector_type(8))) __bf16 bf16x8;
typedef __attribute__((ext_vector_type(4))) __bf16 bf16x4;
typedef __attribute__((ext_vector_type(4))) float f32x4;

__device__ __forceinline__ void gload16(const void* g, void* l) {
  __builtin_amdgcn_global_load_lds(
      (__attribute__((address_space(1))) void*)(g),
      (__attribute__((address_space(3))) void*)(l), 16, 0, 0);
}

// ---------------------------------------------------------------------------
// Workspace layout (bytes):
//   xh  : NHWC padded input, bf16 [130][130][512]        = 17,305,600
//   w1t : conv1 weights,     bf16 [9][512 oc][512 c]     =  4,718,592
//   w2p : packed head wts,   bf16 [80 oc2][512 c]        =     81,920
//   mid : conv1 output NHWC, bf16 [16384 px][512 oc]     = 16,777,216
// ---------------------------------------------------------------------------
#define WS_XH   0
#define WS_W1T  17305600
#define WS_W2P  22024192
#define WS_MID  22106112

#define OUT_CLS 786432
#define OUT_ROI 1179648

// ---------------- prep: border | w1 repack (wide stores) | w2 | transpose --
// grid = 132 + 256 + 160 + 2048 = 2596 blocks, 256 thr
__global__ __launch_bounds__(256) void prep_all(
    int4* __restrict__ xh4, const float* __restrict__ w1,
    bf16* __restrict__ w1t, const float* __restrict__ loc_w,
    const float* __restrict__ score_w, bf16* __restrict__ w2p,
    const float* __restrict__ x, bf16* __restrict__ xh) {
  __shared__ __align__(16) char smem[36864];
  float (*lds)[65] = (float(*)[65])smem;
  float* ldsf = (float*)smem;
  const int t = threadIdx.x;
  const int b = blockIdx.x;
  if (b < 132) {                       // ---- xh halo border zeroing
    const int4 z = make_int4(0, 0, 0, 0);
    if (b < 130) {
      if (t < 64)       xh4[(b * 130 + 0) * 64 + t] = z;
      else if (t < 128) xh4[(b * 130 + 129) * 64 + (t - 64)] = z;
    } else {
      const int r = (b == 130) ? 0 : 129;
      for (int i = t; i < 8320; i += 256) xh4[r * 8320 + i] = z;
    }
  } else if (b < 388) {                // ---- w1 -> w1t[j][oc][c], bf16x4 stores
    const int bb = b - 132;            // 0..255, block = 1024 (oc,c) pairs
    const float4* src = (const float4*)(w1 + (long)bb * 9216);
    float4* dst4 = (float4*)ldsf;
#pragma unroll
    for (int i = 0; i < 9; ++i) dst4[i * 256 + t] = src[i * 256 + t];
    __syncthreads();
    const int p0 = bb * 1024 + 4 * t;  // pair = oc*512 + c
#pragma unroll
    for (int j = 0; j < 9; ++j) {
      bf16x4 v;
#pragma unroll
      for (int e = 0; e < 4; ++e) v[e] = (bf16)ldsf[(4 * t + e) * 9 + j];
      *(bf16x4*)(w1t + (long)j * 262144 + p0) = v;
    }
  } else if (b < 548) {                // ---- pack -> w2p[80][512]
    const int idx = (b - 388) * 256 + t;
    const int c  = idx & 511;
    const int oc = idx >> 9;
    float v = 0.f;
    if (oc < 48)      v = loc_w[oc * 512 + c];
    else if (oc < 72) v = score_w[(oc - 48) * 512 + c];
    w2p[idx] = (bf16)v;
  } else {                             // ---- NCHW f32 -> NHWC bf16 transpose
    const int bb   = b - 548;
    const int ct   = bb & 7;
    const int colt = (bb >> 3) & 1;
    const int r    = 1 + (bb >> 4);
    const int c0   = ct * 64;
    const int col0 = 1 + colt * 64;
    const int lcol = t & 63;
    const int coff = t >> 6;
#pragma unroll
    for (int i = 0; i < 16; ++i) {
      const int cl = coff + i * 4;
      lds[cl][lcol] = x[(long)(c0 + cl) * 16384 + (r - 1) * 128 + (col0 - 1) + lcol];
    }
    __syncthreads();
#pragma unroll
    for (int i = 0; i < 2; ++i) {
      const int idx = i * 256 + t;
      const int pxl = idx >> 3;
      const int oct = idx & 7;
      bf16x8 v;
#pragma unroll
      for (int e = 0; e < 8; ++e) v[e] = (bf16)lds[oct * 8 + e][pxl];
      *(bf16x8*)(xh + (long)(r * 130 + col0 + pxl) * 512 + c0 + oct * 8) = v;
    }
  }
}

// ---------------- conv1: hybrid A-direct / B-LDS, 3-deep pipeline ----------
// Round-6/9 analysis: 797 cyc/block-slot == 48 KB LDS traffic at the ~60 B/cyc
// mixed read+DMA ceiling. Fix: A-fragments bypass LDS entirely -> direct
// global->VGPR loads (A-tiles are 8 KB/slot, reused by 128 h-blocks -> L2/L1
// hot). LDS carries only B (16 KB frag reads + 8 KB DMA per block-slot).
// Pipeline: 3-deep rotation; per stage 6 vm-ops/wave (2 B-DMA + 4 A-loads);
// s_waitcnt vmcnt(6) = oldest stage complete, newest stays in flight.
__global__ __launch_bounds__(256, 2) void conv1_gemm(
    const bf16* __restrict__ w1t, const bf16* __restrict__ xh,
    const float* __restrict__ b1, bf16* __restrict__ mid) {
  __shared__ bf16 B0[4096], B1[4096], B2[4096];   // 8 KB each: 128px x 32c
  const int tid  = threadIdx.x;
  const int wave = tid >> 6;
  const int lane = tid & 63;
  const int quad = lane >> 4;
  const int l15  = lane & 15;
  const int wr = wave >> 1, wc = wave & 1;
  const int blk     = blockIdx.x;
  const int oc_tile = blk >> 7;
  const int hraw    = blk & 127;
  const int h       = ((hraw & 7) << 4) + (hraw >> 3);   // XCD h-band swizzle
  const char* w1tB = (const char*)w1t + (long)oc_tile * 131072;
  const char* xhB  = (const char*)xh;
  const int srow = lane >> 2;                               // 16 rows/call
  const int ssw  = (((lane & 3) ^ ((lane >> 3) & 3)) << 4); // swizzled chunk
  const int swq  = (quad ^ ((l15 >> 1) & 3)) << 3;          // swizzled frag

  // per-lane constant part of the A addresses (row select + quad chunk)
  const long aLane = (long)(wr * 64 + l15) * 1024 + quad * 16;

  bf16x8 a0[4], a1[4], a2[4];

  auto stage = [&](int s, bf16x8* ar, bf16* Bt) {   // 6 vm-ops per wave
    const int j  = s >> 4, ck = s & 15;
    const int ky = j / 3, kx = j - ky * 3;
    const char* bB = xhB + (long)((h + ky) * 130 + kx) * 1024 + ck * 64;
#pragma unroll
    for (int c = 0; c < 2; ++c) {                   // B: 128 rows, 2 calls/wave
      const int r0 = wave * 32 + c * 16;
      gload16(bB + (long)(r0 + srow) * 1024 + ssw, (char*)Bt + r0 * 64);
    }
    const char* aB = w1tB + (long)j * 524288 + ck * 64 + aLane;
#pragma unroll
    for (int mi = 0; mi < 4; ++mi)                  // A: direct to VGPR
      ar[mi] = *(const bf16x8*)(aB + mi * 16384);
  };

  f32x4 acc[4][4];
#pragma unroll
  for (int i = 0; i < 4; ++i)
#pragma unroll
    for (int k = 0; k < 4; ++k) acc[i][k] = (f32x4){0.f, 0.f, 0.f, 0.f};

  auto compute = [&](const bf16x8* ar, const bf16* B) {
    bf16x8 bfr[4];
#pragma unroll
    for (int ni = 0; ni < 4; ++ni)
      bfr[ni] = *(const bf16x8*)&B[(wc * 64 + ni * 16 + l15) * 32 + swq];
#pragma unroll
    for (int mi = 0; mi < 4; ++mi)
#pragma unroll
      for (int ni = 0; ni < 4; ++ni)
        acc[mi][ni] = __builtin_amdgcn_mfma_f32_16x16x32_bf16(
            ar[mi], bfr[ni], acc[mi][ni], 0, 0, 0);
  };

#define WAIT6 asm volatile("s_waitcnt vmcnt(6)" ::: "memory")
#define WAIT0 asm volatile("s_waitcnt vmcnt(0)" ::: "memory")
#define BARR  __builtin_amdgcn_s_barrier()

  stage(0, a0, B0);
  stage(1, a1, B1);
  for (int g = 0; g < 47; ++g) {        // slots 0..140
    const int s = g * 3;
    WAIT6; BARR; stage(s + 2, a2, B2); compute(a0, B0);
    WAIT6; BARR; stage(s + 3, a0, B0); compute(a1, B1);
    WAIT6; BARR; stage(s + 4, a1, B1); compute(a2, B2);
  }
  WAIT6; BARR; stage(143, a2, B2); compute(a0, B0);     // slot 141
  WAIT6; BARR; compute(a1, B1);                         // slot 142
  WAIT0; BARR; compute(a2, B2);                         // slot 143

#undef WAIT6
#undef WAIT0
#undef BARR

  // epilogue: bias + relu, store bf16 NHWC mid[px][oc]
#pragma unroll
  for (int mi = 0; mi < 4; ++mi) {
    const int oc = oc_tile * 128 + wr * 64 + mi * 16 + quad * 4;
    const float bv0 = b1[oc], bv1 = b1[oc + 1], bv2 = b1[oc + 2], bv3 = b1[oc + 3];
#pragma unroll
    for (int ni = 0; ni < 4; ++ni) {
      const int px = wc * 64 + ni * 16 + l15;
      f32x4 a = acc[mi][ni];
      float t0 = a[0] + bv0; t0 = t0 > 0.f ? t0 : 0.f;
      float t1 = a[1] + bv1; t1 = t1 > 0.f ? t1 : 0.f;
      float t2 = a[2] + bv2; t2 = t2 > 0.f ? t2 : 0.f;
      float t3 = a[3] + bv3; t3 = t3 > 0.f ? t3 : 0.f;
      bf16x4 v = {(bf16)t0, (bf16)t1, (bf16)t2, (bf16)t3};
      *(bf16x4*)(mid + (long)(h * 128 + px) * 512 + oc) = v;
    }
  }
}

// ---------------- head: barrier-free K-split GEMM + anchor decode ----------
__global__ __launch_bounds__(256) void head_gemm(
    const bf16* __restrict__ w2p, const bf16* __restrict__ mid,
    const float* __restrict__ loc_b, const float* __restrict__ score_b,
    float* __restrict__ out) {
  __shared__ f32x4 red[3][64][5];
  const int tid  = threadIdx.x;
  const int wave = tid >> 6;
  const int lane = tid & 63;
  const int quad = lane >> 4;
  const int l15  = lane & 15;
  const int px0  = blockIdx.x * 16;
  const bf16* mB = mid + (long)px0 * 512;

  f32x4 acc[5];
#pragma unroll
  for (int i = 0; i < 5; ++i) acc[i] = (f32x4){0.f, 0.f, 0.f, 0.f};

#pragma unroll
  for (int st = 0; st < 4; ++st) {
    const int k0 = wave * 128 + st * 32;
    bf16x8 bfr = *(const bf16x8*)(mB + (long)l15 * 512 + k0 + quad * 8);
#pragma unroll
    for (int mi = 0; mi < 5; ++mi) {
      bf16x8 af = *(const bf16x8*)(w2p + (long)(mi * 16 + l15) * 512 + k0 + quad * 8);
      acc[mi] = __builtin_amdgcn_mfma_f32_16x16x32_bf16(af, bfr, acc[mi], 0, 0, 0);
    }
  }

  if (wave > 0) {
#pragma unroll
    for (int mi = 0; mi < 5; ++mi) red[wave - 1][lane][mi] = acc[mi];
  }
  __syncthreads();
  if (wave != 0) return;
#pragma unroll
  for (int w = 0; w < 3; ++w)
#pragma unroll
    for (int mi = 0; mi < 5; ++mi) acc[mi] += red[w][lane][mi];

  const int p    = px0 + l15;
  const int hh   = p >> 7;
  const int wcol = p & 127;
  const float cx = 16.f * (float)hh;
  const float cy = 16.f * (float)wcol;
  const float s0 = quad == 0 ? 45.f : quad == 1 ? 91.f : quad == 2 ? 181.f : 362.f;
  const float s1 = quad == 0 ? 32.f : quad == 1 ? 64.f : quad == 2 ? 128.f : 256.f;
  const float s2 = quad == 0 ? 23.f : quad == 1 ? 45.f : quad == 2 ? 91.f : 181.f;
  const float aw[3] = {s0, s1, s2};
  const float ah[3] = {s2, s1, s0};
#pragma unroll
  for (int mi = 0; mi < 5; ++mi) {
#pragma unroll
    for (int r = 0; r < 4; ++r) {
      const int oc2 = mi * 16 + quad * 4 + r;
      float v = acc[mi][r];
      if (mi < 3) {
        v += loc_b[oc2];
        out[p * 48 + oc2] = v;
        float roi;
        if (r == 0)      roi = v * aw[mi] + cx;
        else if (r == 1) roi = v * ah[mi] + cy;
        else if (r == 2) roi = __expf(v) * aw[mi];
        else             roi = __expf(v) * ah[mi];
        out[OUT_ROI + p * 48 + oc2] = roi;
      } else {
        const int sc = oc2 - 48;
        if (sc < 24) {
          v += score_b[sc];
          out[OUT_CLS + p * 24 + sc] = v;
        }
      }
    }
  }
}

// ---------------------------------------------------------------------------
extern "C" void kernel_launch(void* const* d_in, const int* in_sizes, int n_in,
                              void* d_out, int out_size, void* d_ws, size_t ws_size,
                              hipStream_t stream) {
  (void)in_sizes; (void)n_in; (void)out_size; (void)ws_size;
  const float* x       = (const float*)d_in[0];
  const float* conv1_w = (const float*)d_in[1];
  const float* conv1_b = (const float*)d_in[2];
  const float* score_w = (const float*)d_in[3];
  const float* score_b = (const float*)d_in[4];
  const float* loc_w   = (const float*)d_in[5];
  const float* loc_b   = (const float*)d_in[6];
  char* ws = (char*)d_ws;
  bf16* xh  = (bf16*)(ws + WS_XH);
  bf16* w1t = (bf16*)(ws + WS_W1T);
  bf16* w2p = (bf16*)(ws + WS_W2P);
  bf16* mid = (bf16*)(ws + WS_MID);
  float* out = (float*)d_out;

  hipLaunchKernelGGL(prep_all,   dim3(2596), dim3(256), 0, stream,
                     (int4*)xh, conv1_w, w1t, loc_w, score_w, w2p, x, xh);
  hipLaunchKernelGGL(conv1_gemm, dim3(512),  dim3(256), 0, stream,
                     w1t, xh, conv1_b, mid);
  hipLaunchKernelGGL(head_gemm,  dim3(1024), dim3(256), 0, stream,
                     w2p, mid, loc_b, score_b, out);
}